// Round 3
// baseline (24487.509 us; speedup 1.0000x reference)
//
#include <hip/hip_runtime.h>

// LSTM B=32, T=2048, D=256, H=256. relu(x) -> single-layer LSTM (i,f,g,o).
// Persistent kernel: 16 blocks = 2 batch-groups (16 batches) x 8 parts.
// Part p holds W_ih/W_hh rows for hidden units [32p,32p+32) x 4 gates (128 rows)
// as bf16 MFMA B-fragments in registers.
// R3 change: flags eliminated. h is published as SELF-VALIDATING tagged words:
// u32 = (bf16(h) << 16) | (step & 0xffff), parity double-buffered. Readers
// poll the data words directly (relaxed agent-scope atomics, read-through to
// the coherence point) until all tags match the step. One visibility hop per
// step instead of three (h-store ack -> flag store -> flag poll + h load).
// Safety of slot reuse: slot (s&1) is overwritten with h(s+2) only after all
// parts published h(s+1), which implies every part consumed h(s).

#define T_STEPS 2048
#define DDIM 256
#define HDIM 256
#define GROUPS 2
#define PARTS 8
#define NBLOCKS (GROUPS * PARTS)
#define NTHREADS 512

typedef __attribute__((ext_vector_type(8))) short short8;
typedef __attribute__((ext_vector_type(4))) float float4_;
typedef __attribute__((ext_vector_type(2))) float float2_;

__device__ inline unsigned short f2bf(float f) {
    unsigned u = __float_as_uint(f);
    return (unsigned short)((u + 0x7fffu + ((u >> 16) & 1u)) >> 16);
}
__device__ inline float sigmoid_f(float x) { return 1.f / (1.f + __expf(-x)); }
__device__ inline float tanh_f(float x) { return 1.f - 2.f / (__expf(2.f * x) + 1.f); }

__global__ __launch_bounds__(NTHREADS, 1)
void lstm_persistent(const float* __restrict__ x,
                     const float* __restrict__ Wih,
                     const float* __restrict__ Whh,
                     const float* __restrict__ bih,
                     const float* __restrict__ bhh,
                     float* __restrict__ out,
                     unsigned int* __restrict__ hbuf)  // [2 par][2 grp][16 b][256 u] tagged u32
{
    const int tid  = threadIdx.x;
    const int blk  = blockIdx.x;
    const int g    = blk >> 3;   // batch group
    const int p    = blk & 7;    // part (hidden-unit slice)
    const int w    = tid >> 6;   // wave 0..7, one 16x16 N-tile each
    const int lane = tid & 63;
    const int c16  = lane & 15;
    const int quad = lane >> 4;

    __shared__ float gatesLds[128 * 17];
    __shared__ float biasLds[128];

    if (tid < 128) {
        int n = ((tid >> 5) << 8) + (p << 5) + (tid & 31);
        biasLds[tid] = bih[n] + bhh[n];
    }

    // ---- weight fragment preload (registers, bf16) ----
    const int r_row = (w << 4) + c16;                                // local row 0..127
    const int wrow  = ((r_row >> 5) << 8) + (p << 5) + (r_row & 31); // global W row
    const int k0    = quad << 3;

    short8 wih_f[8], whh_f[8];
#pragma unroll
    for (int kt = 0; kt < 8; ++kt) {
        const float* s1 = Wih + wrow * DDIM + kt * 32 + k0;
        const float* s2 = Whh + wrow * HDIM + kt * 32 + k0;
        short8 v1, v2;
#pragma unroll
        for (int j = 0; j < 8; ++j) { v1[j] = (short)f2bf(s1[j]); v2[j] = (short)f2bf(s2[j]); }
        wih_f[kt] = v1;
        whh_f[kt] = v2;
    }

    // ---- x prefetch: A-frag lane m = lane&15 = batch-in-group ----
    const float* xlane = x + (size_t)(g * 16 + c16) * (size_t)(T_STEPS * DDIM);
    float4_ xraw[16];
#pragma unroll
    for (int kt = 0; kt < 8; ++kt) {
        const float* sx = xlane + kt * 32 + k0;
        xraw[2 * kt]     = *(const float4_*)(sx);
        xraw[2 * kt + 1] = *(const float4_*)(sx + 4);
    }

    // epilogue mapping: threads 0..255, 2 adjacent units each
    const int b_e = tid & 15;
    const int up  = (tid >> 4) & 15;
    float c0 = 0.f, c1 = 0.f;

    for (int s = 0; s < T_STEPS; ++s) {
        // ---- x convert (relu + bf16) + x-MFMAs: independent of h
        short8 xf[8];
#pragma unroll
        for (int kt = 0; kt < 8; ++kt) {
            short8 v;
#pragma unroll
            for (int j = 0; j < 4; ++j) {
                float a = xraw[2 * kt][j];
                float b = xraw[2 * kt + 1][j];
                v[j]     = (short)f2bf(a > 0.f ? a : 0.f);
                v[j + 4] = (short)f2bf(b > 0.f ? b : 0.f);
            }
            xf[kt] = v;
        }
        float4_ acc0 = {0.f, 0.f, 0.f, 0.f};
        float4_ acc1 = {0.f, 0.f, 0.f, 0.f};
#pragma unroll
        for (int kt = 0; kt < 8; kt += 2) {
            acc0 = __builtin_amdgcn_mfma_f32_16x16x32_bf16(xf[kt],     wih_f[kt],     acc0, 0, 0, 0);
            acc1 = __builtin_amdgcn_mfma_f32_16x16x32_bf16(xf[kt + 1], wih_f[kt + 1], acc1, 0, 0, 0);
        }
        // prefetch next step's x
        {
            int sn = (s + 1 < T_STEPS) ? s + 1 : s;
            const float* sx = xlane + (size_t)sn * DDIM + k0;
#pragma unroll
            for (int kt = 0; kt < 8; ++kt) {
                xraw[2 * kt]     = *(const float4_*)(sx + kt * 32);
                xraw[2 * kt + 1] = *(const float4_*)(sx + kt * 32 + 4);
            }
        }

        // ---- poll tagged h(s) A-frag directly (one visibility hop) ----
        // word layout: [(s&1)*2 + g][batch c16][unit]; lane covers units
        // kt*32 + k0 .. +7 per kt  ->  4 qwords per kt, 32 qword loads total.
        const unsigned long long* hq = (const unsigned long long*)
            (hbuf + ((((s & 1) * 2 + g) * 16 + c16) << 8) + k0);
        const unsigned tag = (unsigned)s & 0xffffu;
        short8 hf[8];
        {
            unsigned bad;
            do {
                bad = 0u;
#pragma unroll
                for (int kt = 0; kt < 8; ++kt) {
                    short8 v;
#pragma unroll
                    for (int hh = 0; hh < 4; ++hh) {
                        unsigned long long q = __hip_atomic_load(
                            hq + kt * 16 + hh, __ATOMIC_RELAXED, __HIP_MEMORY_SCOPE_AGENT);
                        unsigned lo = (unsigned)q;
                        unsigned hi = (unsigned)(q >> 32);
                        bad |= (lo ^ tag) & 0xffffu;
                        bad |= (hi ^ tag) & 0xffffu;
                        v[2 * hh]     = (short)(lo >> 16);
                        v[2 * hh + 1] = (short)(hi >> 16);
                    }
                    hf[kt] = v;
                }
            } while (bad != 0u);
        }

#pragma unroll
        for (int kt = 0; kt < 8; kt += 2) {
            acc0 = __builtin_amdgcn_mfma_f32_16x16x32_bf16(hf[kt],     whh_f[kt],     acc0, 0, 0, 0);
            acc1 = __builtin_amdgcn_mfma_f32_16x16x32_bf16(hf[kt + 1], whh_f[kt + 1], acc1, 0, 0, 0);
        }

        __syncthreads();   // prev-iter gatesLds reads complete before overwrite
        // D layout: col = lane&15 = local row r_row, row = quad*4+j = batch
#pragma unroll
        for (int j = 0; j < 4; ++j)
            gatesLds[r_row * 17 + (quad << 2) + j] = acc0[j] + acc1[j];
        __syncthreads();

        // ---- elementwise LSTM cell update: threads 0..255, 2 units each
        if (tid < 256) {
            const int u0 = up << 1, u1 = u0 + 1;
            float gi0 = gatesLds[u0 * 17 + b_e]         + biasLds[u0];
            float gf0 = gatesLds[(32 + u0) * 17 + b_e]  + biasLds[32 + u0];
            float gg0 = gatesLds[(64 + u0) * 17 + b_e]  + biasLds[64 + u0];
            float go0 = gatesLds[(96 + u0) * 17 + b_e]  + biasLds[96 + u0];
            float gi1 = gatesLds[u1 * 17 + b_e]         + biasLds[u1];
            float gf1 = gatesLds[(32 + u1) * 17 + b_e]  + biasLds[32 + u1];
            float gg1 = gatesLds[(64 + u1) * 17 + b_e]  + biasLds[64 + u1];
            float go1 = gatesLds[(96 + u1) * 17 + b_e]  + biasLds[96 + u1];

            c0 = sigmoid_f(gf0) * c0 + sigmoid_f(gi0) * tanh_f(gg0);
            c1 = sigmoid_f(gf1) * c1 + sigmoid_f(gi1) * tanh_f(gg1);
            float h0 = sigmoid_f(go0) * tanh_f(c0);
            float h1 = sigmoid_f(go1) * tanh_f(c1);

            // publish tagged h(s+1): one 8B relaxed agent store (write-through)
            unsigned ntag = (unsigned)(s + 1) & 0xffffu;
            unsigned long long pv =
                ((unsigned long long)(((unsigned)f2bf(h1) << 16) | ntag) << 32) |
                (unsigned long long)(((unsigned)f2bf(h0) << 16) | ntag);
            unsigned long long* hd = (unsigned long long*)
                (hbuf + (((((s + 1) & 1) * 2 + g) * 16 + b_e) << 8) + (p << 5) + u0);
            __hip_atomic_store(hd, pv, __ATOMIC_RELAXED, __HIP_MEMORY_SCOPE_AGENT);

            float2_ ov = {h0, h1};
            *(float2_*)(out + ((size_t)(g * 16 + b_e) * T_STEPS + (size_t)s) * HDIM + (p << 5) + u0) = ov;
        }
        // no end-of-step fence/flag: tagged words self-validate
    }
}

extern "C" void kernel_launch(void* const* d_in, const int* in_sizes, int n_in,
                              void* d_out, int out_size, void* d_ws, size_t ws_size,
                              hipStream_t stream) {
    (void)in_sizes; (void)n_in; (void)out_size; (void)ws_size;
    const float* x   = (const float*)d_in[0];
    const float* Wih = (const float*)d_in[1];
    const float* Whh = (const float*)d_in[2];
    const float* bih = (const float*)d_in[3];
    const float* bhh = (const float*)d_in[4];
    float* out = (float*)d_out;

    unsigned int* hbuf = (unsigned int*)d_ws;   // 2*2*16*256*4 = 64 KiB

    hipMemsetAsync(d_ws, 0, 65536, stream);
    hipLaunchKernelGGL(lstm_persistent, dim3(NBLOCKS), dim3(NTHREADS), 0, stream,
                       x, Wih, Whh, bih, bhh, out, hbuf);
}

// Round 4
// 18563.951 us; speedup vs baseline: 1.3191x; 1.3191x over previous
//
#include <hip/hip_runtime.h>

// LSTM B=32, T=2048, D=256, H=256. relu(x) -> single-layer LSTM (i,f,g,o).
// R4: batch-parallel split -> ZERO cross-block communication.
//  Phase 1 (grid-wide): xg[t][b][4H] = relu(x)@Wih^T + bih + bhh  (ws, fp32).
//  Phase 2 (scan): 2 blocks x 1024 thr, one per 16-batch group, self-contained
//  on one CU. Whh in registers as MFMA B-frags; h through LDS double buffer;
//  ONE __syncthreads per step. Gate-tile N-mapping (wave w, lane c16 -> unit
//  u=16w+c16; tiles = gate types) makes the epilogue register-local:
//  lane holds i,f,g,o for (batches quad*4+j, unit u); c-state in registers.
//  Fallback (ws too small): scan<false> fuses the x-projection MFMAs.

#define T_STEPS 2048
#define B_ALL 32
#define DDIM 256
#define HDIM 256
#define NGATES 1024
#define HPAD 264   // 256 + 8 bf16 pad: breaks power-of-2 LDS bank stride

typedef __attribute__((ext_vector_type(8))) short short8;
typedef __attribute__((ext_vector_type(4))) float float4_;

__device__ inline unsigned short f2bf(float f) {
    unsigned u = __float_as_uint(f);
    return (unsigned short)((u + 0x7fffu + ((u >> 16) & 1u)) >> 16);
}
__device__ inline float sigmoid_f(float x) { return 1.f / (1.f + __expf(-x)); }
__device__ inline float tanh_f(float x) { return 1.f - 2.f / (__expf(2.f * x) + 1.f); }

// ---------------- Phase 1: xg = relu(x)@Wih^T + bih + bhh  ------------------
// grid (256, 2): block = 8 timesteps x 16 batches x all 1024 gates.
__global__ __launch_bounds__(1024, 4)
void lstm_xg_gemm(const float* __restrict__ x,
                  const float* __restrict__ Wih,
                  const float* __restrict__ bih,
                  const float* __restrict__ bhh,
                  float* __restrict__ xg)
{
    const int tid  = threadIdx.x;
    const int w    = tid >> 6;
    const int lane = tid & 63;
    const int c16  = lane & 15;
    const int quad = lane >> 4;
    const int t0   = blockIdx.x << 3;
    const int bh   = blockIdx.y;

    // B-frags: wave w covers N in [64w, 64w+64), 4 tiles of 16
    short8 wf[4][8];
    float  bias[4];
#pragma unroll
    for (int tt = 0; tt < 4; ++tt) {
        const int r = (w << 6) + (tt << 4) + c16;
        bias[tt] = bih[r] + bhh[r];
        const float* src = Wih + (size_t)r * DDIM + (quad << 3);
#pragma unroll
        for (int kt = 0; kt < 8; ++kt) {
            short8 v;
#pragma unroll
            for (int j = 0; j < 8; ++j) v[j] = (short)f2bf(src[kt * 32 + j]);
            wf[tt][kt] = v;
        }
    }

    const int b_a = (bh << 4) + c16;   // A-frag batch (row m = c16)
    for (int t = 0; t < 8; ++t) {
        const float* xs = x + ((size_t)b_a * T_STEPS + (t0 + t)) * DDIM + (quad << 3);
        short8 xf[8];
#pragma unroll
        for (int kt = 0; kt < 8; ++kt) {
            short8 v;
#pragma unroll
            for (int j = 0; j < 8; ++j) {
                float a = xs[kt * 32 + j];
                v[j] = (short)f2bf(a > 0.f ? a : 0.f);
            }
            xf[kt] = v;
        }
        float4_ z = {0.f, 0.f, 0.f, 0.f};
        float4_ acc[4] = {z, z, z, z};
#pragma unroll
        for (int kt = 0; kt < 8; ++kt)
#pragma unroll
            for (int tt = 0; tt < 4; ++tt)
                acc[tt] = __builtin_amdgcn_mfma_f32_16x16x32_bf16(xf[kt], wf[tt][kt], acc[tt], 0, 0, 0);
        // D: col=c16 -> n, row=quad*4+j -> batch
#pragma unroll
        for (int tt = 0; tt < 4; ++tt) {
            const int n = (w << 6) + (tt << 4) + c16;
#pragma unroll
            for (int j = 0; j < 4; ++j) {
                const int bb = (bh << 4) + (quad << 2) + j;
                xg[((size_t)(t0 + t) * B_ALL + bb) * NGATES + n] = acc[tt][j] + bias[tt];
            }
        }
    }
}

// ---------------- Phase 2: the scan -----------------------------------------
template <bool USE_XG>
__global__ __launch_bounds__(1024, 4)
void lstm_scan(const float* __restrict__ x,
               const float* __restrict__ Wih,
               const float* __restrict__ Whh,
               const float* __restrict__ bih,
               const float* __restrict__ bhh,
               const float* __restrict__ xg,
               float* __restrict__ out)
{
    const int tid  = threadIdx.x;
    const int g    = blockIdx.x;        // batch group of 16
    const int w    = tid >> 6;
    const int lane = tid & 63;
    const int c16  = lane & 15;
    const int quad = lane >> 4;
    const int u    = (w << 4) + c16;    // this lane's hidden unit

    __shared__ __align__(16) unsigned short hbuf[2][16][HPAD];

    // zero both h parity buffers (h(0)=0)
    {
        unsigned* hz = (unsigned*)hbuf;
        for (int i = tid; i < 2 * 16 * HPAD / 2; i += 1024) hz[i] = 0u;
    }

    // Whh B-frags: 4 gate tiles for unit u; rows r = gt*256 + u
    short8 whh_f[4][8];
    float  bias_r[4];
#pragma unroll
    for (int gt = 0; gt < 4; ++gt) {
        const int r = (gt << 8) + u;
        bias_r[gt] = bih[r] + bhh[r];
        const float* src = Whh + (size_t)r * HDIM + (quad << 3);
#pragma unroll
        for (int kt = 0; kt < 8; ++kt) {
            short8 v;
#pragma unroll
            for (int j = 0; j < 8; ++j) v[j] = (short)f2bf(src[kt * 32 + j]);
            whh_f[gt][kt] = v;
        }
    }

    // fused path: Wih B-frags too
    short8 wih_f[4][8];
    if constexpr (!USE_XG) {
#pragma unroll
        for (int gt = 0; gt < 4; ++gt) {
            const int r = (gt << 8) + u;
            const float* src = Wih + (size_t)r * DDIM + (quad << 3);
#pragma unroll
            for (int kt = 0; kt < 8; ++kt) {
                short8 v;
#pragma unroll
                for (int j = 0; j < 8; ++j) v[j] = (short)f2bf(src[kt * 32 + j]);
                wih_f[gt][kt] = v;
            }
        }
    }

    // xg prefetch registers (xg includes biases)
    const float* xg_base = xg + (size_t)((g << 4) + (quad << 2)) * NGATES + u;
    float xg_cur[16], xg_nxt[16];
    if constexpr (USE_XG) {
#pragma unroll
        for (int gt = 0; gt < 4; ++gt)
#pragma unroll
            for (int j = 0; j < 4; ++j)
                xg_cur[(gt << 2) + j] = xg_base[(size_t)j * NGATES + (gt << 8)];
    }

    // fused path: x prefetch (A-frag: lane c16 = batch)
    const float* xlane = x + (size_t)((g << 4) + c16) * T_STEPS * DDIM + (quad << 3);
    float4_ xraw[16];
    if constexpr (!USE_XG) {
#pragma unroll
        for (int kt = 0; kt < 8; ++kt) {
            xraw[2 * kt]     = *(const float4_*)(xlane + kt * 32);
            xraw[2 * kt + 1] = *(const float4_*)(xlane + kt * 32 + 4);
        }
    }

    float c_state[4] = {0.f, 0.f, 0.f, 0.f};
    __syncthreads();

    for (int s = 0; s < T_STEPS; ++s) {
        // prefetch next step's xg (off critical path; consumed next iter)
        if constexpr (USE_XG) {
            const float* xp = xg_base + (size_t)(s + 1 < T_STEPS ? s + 1 : s) * (B_ALL * NGATES);
#pragma unroll
            for (int gt = 0; gt < 4; ++gt)
#pragma unroll
                for (int j = 0; j < 4; ++j)
                    xg_nxt[(gt << 2) + j] = xp[(size_t)j * NGATES + (gt << 8)];
        }

        float4_ z = {0.f, 0.f, 0.f, 0.f};
        float4_ acc[4] = {z, z, z, z};

        if constexpr (!USE_XG) {
            short8 xf[8];
#pragma unroll
            for (int kt = 0; kt < 8; ++kt) {
                short8 v;
#pragma unroll
                for (int j = 0; j < 4; ++j) {
                    float a = xraw[2 * kt][j];
                    float b = xraw[2 * kt + 1][j];
                    v[j]     = (short)f2bf(a > 0.f ? a : 0.f);
                    v[j + 4] = (short)f2bf(b > 0.f ? b : 0.f);
                }
                xf[kt] = v;
            }
            {   // prefetch next x
                const int sn = (s + 1 < T_STEPS) ? s + 1 : s;
                const float* sx = xlane + (size_t)sn * DDIM;
#pragma unroll
                for (int kt = 0; kt < 8; ++kt) {
                    xraw[2 * kt]     = *(const float4_*)(sx + kt * 32);
                    xraw[2 * kt + 1] = *(const float4_*)(sx + kt * 32 + 4);
                }
            }
#pragma unroll
            for (int kt = 0; kt < 8; ++kt)
#pragma unroll
                for (int gt = 0; gt < 4; ++gt)
                    acc[gt] = __builtin_amdgcn_mfma_f32_16x16x32_bf16(xf[kt], wih_f[gt][kt], acc[gt], 0, 0, 0);
        }

        // h(s) A-frags from LDS (lane c16 = batch, k = kt*32 + quad*8 + j)
        short8 hf[8];
#pragma unroll
        for (int kt = 0; kt < 8; ++kt)
            hf[kt] = *(const short8*)&hbuf[s & 1][c16][(kt << 5) + (quad << 3)];

#pragma unroll
        for (int kt = 0; kt < 8; ++kt)
#pragma unroll
            for (int gt = 0; gt < 4; ++gt)
                acc[gt] = __builtin_amdgcn_mfma_f32_16x16x32_bf16(hf[kt], whh_f[gt][kt], acc[gt], 0, 0, 0);

        // register-local epilogue: lane owns (batches quad*4+j, unit u)
        unsigned short* hw = &hbuf[(s + 1) & 1][quad << 2][u];
        float* op = out + ((size_t)((g << 4) + (quad << 2)) * T_STEPS + s) * HDIM + u;
#pragma unroll
        for (int j = 0; j < 4; ++j) {
            float gi = acc[0][j] + (USE_XG ? xg_cur[j]      : bias_r[0]);
            float gf = acc[1][j] + (USE_XG ? xg_cur[4 + j]  : bias_r[1]);
            float gg = acc[2][j] + (USE_XG ? xg_cur[8 + j]  : bias_r[2]);
            float go = acc[3][j] + (USE_XG ? xg_cur[12 + j] : bias_r[3]);
            c_state[j] = sigmoid_f(gf) * c_state[j] + sigmoid_f(gi) * tanh_f(gg);
            float h = sigmoid_f(go) * tanh_f(c_state[j]);
            hw[j * HPAD] = f2bf(h);
            op[(size_t)j * (T_STEPS * HDIM)] = h;
        }

        if constexpr (USE_XG) {
#pragma unroll
            for (int k = 0; k < 16; ++k) xg_cur[k] = xg_nxt[k];
        }
        __syncthreads();   // h(s+1) visible; also guards parity-buffer reuse
    }
}

extern "C" void kernel_launch(void* const* d_in, const int* in_sizes, int n_in,
                              void* d_out, int out_size, void* d_ws, size_t ws_size,
                              hipStream_t stream) {
    (void)in_sizes; (void)n_in; (void)out_size;
    const float* x   = (const float*)d_in[0];
    const float* Wih = (const float*)d_in[1];
    const float* Whh = (const float*)d_in[2];
    const float* bih = (const float*)d_in[3];
    const float* bhh = (const float*)d_in[4];
    float* out = (float*)d_out;

    const size_t xg_bytes = (size_t)T_STEPS * B_ALL * NGATES * sizeof(float); // 256 MiB
    if (ws_size >= xg_bytes) {
        float* xg = (float*)d_ws;
        hipLaunchKernelGGL(lstm_xg_gemm, dim3(T_STEPS / 8, 2), dim3(1024), 0, stream,
                           x, Wih, bih, bhh, xg);
        hipLaunchKernelGGL((lstm_scan<true>), dim3(2), dim3(1024), 0, stream,
                           x, Wih, Whh, bih, bhh, xg, out);
    } else {
        hipLaunchKernelGGL((lstm_scan<false>), dim3(2), dim3(1024), 0, stream,
                           x, Wih, Whh, bih, bhh, (const float*)d_ws, out);
    }
}